// Round 6
// baseline (192.119 us; speedup 1.0000x reference)
//
#include <hip/hip_runtime.h>
#include <stdint.h>

// ---------------- problem constants ----------------
#define T_STEPS 2048
#define BATCH   32
#define NIN     512
#define NOUT    256
#define MROWS   (T_STEPS*BATCH)   // 65536
#define BO      (BATCH*NOUT)      // 8192
#define NCHUNK  32
#define CHLEN   (T_STEPS/NCHUNK)  // 64

typedef _Float16 f16x8 __attribute__((ext_vector_type(8)));
typedef _Float16 f16x4 __attribute__((ext_vector_type(4)));
typedef float    fx4   __attribute__((ext_vector_type(4)));

#define LDSP(p) ((__attribute__((address_space(3))) void*)(p))
#define GLBP(p) ((const __attribute__((address_space(1))) void*)(p))

#define BAR()        asm volatile("s_barrier" ::: "memory")
#define DRAIN_LGKM() asm volatile("s_waitcnt lgkmcnt(0)" ::: "memory")
#define WAITVM(n)    do { asm volatile("s_waitcnt vmcnt(" #n ")" ::: "memory"); __builtin_amdgcn_sched_barrier(0); } while(0)

// ---------------- xt f32 -> f16 ----------------
__global__ __launch_bounds__(256) void convert_x(
    const float* __restrict__ xt, _Float16* __restrict__ xh)
{
    long i = ((long)blockIdx.x * 256 + threadIdx.x) * 8;
    float4 v0 = *(const float4*)(xt + i);
    float4 v1 = *(const float4*)(xt + i + 4);
    f16x8 h;
    h[0] = (_Float16)v0.x; h[1] = (_Float16)v0.y;
    h[2] = (_Float16)v0.z; h[3] = (_Float16)v0.w;
    h[4] = (_Float16)v1.x; h[5] = (_Float16)v1.y;
    h[6] = (_Float16)v1.z; h[7] = (_Float16)v1.w;
    *(f16x8*)(xh + i) = h;
}

// ---------------- weights: 4x [256,512] f32 -> Wcat [1024][512] f16 -------
__global__ __launch_bounds__(256) void convert_w(
    const float* __restrict__ Wx, const float* __restrict__ Wf,
    const float* __restrict__ Wr, const float* __restrict__ Wc,
    _Float16* __restrict__ Wcat)
{
    int idx = blockIdx.x * 256 + threadIdx.x;
    int n  = idx >> 7;
    int k4 = (idx & 127) * 4;
    int g = n >> 8, o = n & 255;
    const float* W = (g == 0) ? Wx : (g == 1) ? Wf : (g == 2) ? Wr : Wc;
    float4 v = *(const float4*)(W + o * NIN + k4);
    f16x4 h;
    h[0] = (_Float16)v.x; h[1] = (_Float16)v.y;
    h[2] = (_Float16)v.z; h[3] = (_Float16)v.w;
    *(f16x4*)(Wcat + n * NIN + k4) = h;
}

// ---------------- persistent 256x256 GEMM, 1-drain/K-step schedule -------
// Per K-tile: {READ h0; lgkm-drain; BAR; STAGE(g+1,h1)+STAGE(g+2,h0);
// READ h1; 64 MFMA (compiler-scheduled fine lgkm waits); vmcnt gate; BAR}.
// All ds_reads are plain loads -> compiler interleaves them + stages under
// the MFMA clusters.  Restage safety: every read drains before the barrier
// preceding its region's restage (h0: this drain; h1: next tile's drain).
#define BM 256
#define BN 256
#define BK 64
#define NGT 32            // 4 m-tiles x 8 k-tiles

__global__ __launch_bounds__(512, 2) void gemm_proj(
    const _Float16* __restrict__ xh,      // [MROWS][512] f16
    const _Float16* __restrict__ Wcat,    // [1024][512]  f16
    const float* __restrict__ bfv, const float* __restrict__ brv, const float* __restrict__ bcv,
    _Float16* __restrict__ xp_h, _Float16* __restrict__ f_h,
    _Float16* __restrict__ r_h,  _Float16* __restrict__ cx_h)
{
    __shared__ char lds[131072];   // A: [c][h] at c*32768+h*16384 ; B: +65536

    const int tid  = threadIdx.x;
    const int lane = tid & 63;
    const int w    = tid >> 6;       // 0..7
    const int wrq  = w >> 2;         // 0..1
    const int wcq  = w & 3;          // 0..3
    const int lr = lane & 15, lk = lane >> 4;

    // XCD-chunked bijective swizzle: 256 wgs, 32/XCD; the 4 cg-blocks of one
    // mgrp are co-XCD (A-tile L2 reuse).
    int wg = (blockIdx.x & 7) * 32 + (blockIdx.x >> 3);
    const int  cg   = wg & 3;        // output group 0..3
    const int  mgrp = wg >> 2;       // 0..63
    const long m0 = (long)mgrp * 1024;   // 4 m-tiles of 256 rows
    const int  n0 = cg * BN;

    const int rl8  = lane >> 3;
    const int scol = (((lane & 7) ^ rl8) << 4);
    const char* baseA = (const char*)xh   + (m0 + w * 8 + rl8) * 1024 + scol;
    const char* baseB = (const char*)Wcat + ((long)(n0 + w * 8 + rl8)) * 1024 + scol;

    // global tile g: mt=g>>3, kt=g&7, LDS parity g&1
#define STAGE_A(g, h) do {                                                   \
        char* _d = lds + ((g) & 1) * 32768 + (h) * 16384 + w * 1024;         \
        const char* _s = baseA + (long)((g) >> 3) * 262144                   \
                         + ((g) & 7) * 128 + (long)(h) * 131072;             \
        __builtin_amdgcn_global_load_lds(GLBP(_s),         LDSP(_d),        16, 0, 0); \
        __builtin_amdgcn_global_load_lds(GLBP(_s + 65536), LDSP(_d + 8192), 16, 0, 0); \
    } while (0)
#define STAGE_B(g, h) do {                                                   \
        char* _d = lds + 65536 + ((g) & 1) * 32768 + (h) * 16384 + w * 1024; \
        const char* _s = baseB + ((g) & 7) * 128 + (long)(h) * 131072;       \
        __builtin_amdgcn_global_load_lds(GLBP(_s),         LDSP(_d),        16, 0, 0); \
        __builtin_amdgcn_global_load_lds(GLBP(_s + 65536), LDSP(_d + 8192), 16, 0, 0); \
    } while (0)

    fx4 acc[2][2][4][2];
    #pragma unroll
    for (int a = 0; a < 2; ++a)
        #pragma unroll
        for (int b = 0; b < 2; ++b)
            #pragma unroll
            for (int c = 0; c < 4; ++c)
                #pragma unroll
                for (int d = 0; d < 2; ++d)
                    acc[a][b][c][d] = (fx4){0.f, 0.f, 0.f, 0.f};

    f16x8 Ar0[4][2];   // A h0 fragments [mf][kk]
    f16x8 Ar1[4][2];   // A h1 fragments
    f16x8 B0r[2][2];   // B h0 fragments [nf][kk]
    f16x8 B1r[2][2];   // B h1 fragments

#define READ_A(c2, h, dst) do {                                              \
        _Pragma("unroll")                                                    \
        for (int mf = 0; mf < 4; ++mf) {                                     \
            int rl = wrq * 64 + mf * 16 + lr;                                \
            int rb = (c2) * 32768 + (h) * 16384 + rl * 128;                  \
            _Pragma("unroll")                                                \
            for (int kk = 0; kk < 2; ++kk)                                   \
                dst[mf][kk] = *(const f16x8*)(lds + rb +                     \
                    ((kk * 64 + lk * 16) ^ ((rl & 7) << 4)));                \
        }                                                                    \
    } while (0)
#define READ_B(c2, h, dst) do {                                              \
        _Pragma("unroll")                                                    \
        for (int nf = 0; nf < 2; ++nf) {                                     \
            int rl = wcq * 32 + nf * 16 + lr;                                \
            int rb = 65536 + (c2) * 32768 + (h) * 16384 + rl * 128;          \
            _Pragma("unroll")                                                \
            for (int kk = 0; kk < 2; ++kk)                                   \
                dst[nf][kk] = *(const f16x8*)(lds + rb +                     \
                    ((kk * 64 + lk * 16) ^ ((rl & 7) << 4)));                \
        }                                                                    \
    } while (0)
    // swapped operands: D[col=lane&15 -> m (A)], [reg j -> o (B)]
#define MMACC(Qr, Qc, Aa, Br) do {                                           \
        _Pragma("unroll")                                                    \
        for (int kk = 0; kk < 2; ++kk)                                       \
            _Pragma("unroll")                                                \
            for (int mf = 0; mf < 4; ++mf)                                   \
                _Pragma("unroll")                                            \
                for (int nf = 0; nf < 2; ++nf)                               \
                    acc[Qr][Qc][mf][nf] = __builtin_amdgcn_mfma_f32_16x16x32_f16( \
                        Br[nf][kk], Aa[mf][kk], acc[Qr][Qc][mf][nf], 0, 0, 0);    \
    } while (0)

    const int g_out = cg;
    _Float16* outp = (g_out == 0) ? xp_h : (g_out == 1) ? f_h : (g_out == 2) ? r_h : cx_h;
    const float* bias = (g_out == 1) ? bfv : (g_out == 2) ? brv : (g_out == 3) ? bcv : nullptr;

    // ---- prologue: tile0 all 4 halves + tile1 h0; land tile0 ----
    STAGE_A(0, 0); STAGE_B(0, 0); STAGE_B(0, 1); STAGE_A(0, 1);
    STAGE_A(1, 0); STAGE_B(1, 0);
    WAITVM(4);
    BAR();

    for (int g = 0; g < NGT; ++g) {
        const int c2 = g & 1;
        // ---- h0 reads ----
        READ_A(c2, 0, Ar0);
        READ_B(c2, 0, B0r);
        DRAIN_LGKM();                  // all waves' h0/h1-of-prev reads done
        BAR();
        // ---- restages (post-drain: safe) + h1 reads + MFMA ----
        if (g + 1 < NGT) { STAGE_B(g + 1, 1); STAGE_A(g + 1, 1); }
        if (g + 2 < NGT) { STAGE_A(g + 2, 0); STAGE_B(g + 2, 0); }
        READ_B(c2, 1, B1r);
        READ_A(c2, 1, Ar1);
        MMACC(0, 0, Ar0, B0r);
        MMACC(0, 1, Ar0, B1r);
        MMACC(1, 0, Ar1, B0r);
        MMACC(1, 1, Ar1, B1r);
        if (g < NGT - 2)       WAITVM(4);
        else if (g == NGT - 2) WAITVM(0);
        BAR();                         // tile g+1 fully landed
        // ---- per-m-tile epilogue (g = mt*8+7): packed f16x4 stores ----
        if ((g & 7) == 7) {
            const long mbase = m0 + (long)(g >> 3) * 256;
            #pragma unroll
            for (int Qr = 0; Qr < 2; ++Qr) {
                #pragma unroll
                for (int Qc = 0; Qc < 2; ++Qc) {
                    #pragma unroll
                    for (int nf = 0; nf < 2; ++nf) {
                        const int ob = Qc * 128 + wcq * 32 + nf * 16 + lk * 4;
                        float4 bv4 = (g_out == 0) ? (float4){0.f, 0.f, 0.f, 0.f}
                                                  : *(const float4*)(bias + ob);
                        #pragma unroll
                        for (int mf = 0; mf < 4; ++mf) {
                            long row = mbase + Qr * 128 + wrq * 64 + mf * 16 + lr;
                            fx4 v = acc[Qr][Qc][mf][nf];
                            f16x4 hv;
                            if (g_out == 1 || g_out == 2) {
                                float p0 = v[0] + bv4.x, p1 = v[1] + bv4.y;
                                float p2 = v[2] + bv4.z, p3 = v[3] + bv4.w;
                                hv[0] = (_Float16)(__builtin_amdgcn_rcpf(1.0f + __expf(-p0)));
                                hv[1] = (_Float16)(__builtin_amdgcn_rcpf(1.0f + __expf(-p1)));
                                hv[2] = (_Float16)(__builtin_amdgcn_rcpf(1.0f + __expf(-p2)));
                                hv[3] = (_Float16)(__builtin_amdgcn_rcpf(1.0f + __expf(-p3)));
                            } else {
                                hv[0] = (_Float16)(v[0] + bv4.x);
                                hv[1] = (_Float16)(v[1] + bv4.y);
                                hv[2] = (_Float16)(v[2] + bv4.z);
                                hv[3] = (_Float16)(v[3] + bv4.w);
                            }
                            *(f16x4*)(outp + row * NOUT + ob) = hv;
                            acc[Qr][Qc][mf][nf] = (fx4){0.f, 0.f, 0.f, 0.f};
                        }
                    }
                }
            }
        }
    }
}

// ---------------- pass 2a: per-chunk affine composition -------------
__global__ __launch_bounds__(256) void chunk_scan_a(
    const _Float16* __restrict__ f_h, const _Float16* __restrict__ xp_h,
    float* __restrict__ chunkA, float* __restrict__ chunkB)
{
    int tid = blockIdx.x * 256 + threadIdx.x;   // 262144
    int chunk = tid >> 13;
    int bo = tid & (BO - 1);
    long base = (long)chunk * CHLEN * BO + bo;
    float a = 1.f, cc = 0.f;
    #pragma unroll 4
    for (int s = 0; s < CHLEN; ++s) {
        long i = base + (long)s * BO;
        float fv = (float)f_h[i];
        float xv = (float)xp_h[i];
        cc = fv * cc + (1.f - fv) * xv;
        a *= fv;
    }
    chunkA[tid] = a;
    chunkB[tid] = cc;
}

// ---------------- pass 2b: propagate chunk states ----
__global__ __launch_bounds__(256) void chunk_prop(
    const float* __restrict__ ct0,
    const float* __restrict__ chunkA, const float* __restrict__ chunkB,
    float* __restrict__ cin, float* __restrict__ c_final)
{
    int bo = blockIdx.x * 256 + threadIdx.x;   // 8192
    float c = ct0[bo];
    #pragma unroll
    for (int ch = 0; ch < NCHUNK; ++ch) {
        cin[ch * BO + bo] = c;
        c = chunkA[ch * BO + bo] * c + chunkB[ch * BO + bo];
    }
    c_final[bo] = c;
}

// ---------------- pass 2c: final scan producing ht -------------------
__global__ __launch_bounds__(256) void chunk_scan_h(
    const _Float16* __restrict__ xp_h, const _Float16* __restrict__ f_h,
    const _Float16* __restrict__ r_h,  const _Float16* __restrict__ cx_h,
    const float* __restrict__ cin, float* __restrict__ ht)
{
    int tid = blockIdx.x * 256 + threadIdx.x;   // 262144
    int chunk = tid >> 13;
    int bo = tid & (BO - 1);
    long base = (long)chunk * CHLEN * BO + bo;
    float c = cin[tid];
    #pragma unroll 4
    for (int s = 0; s < CHLEN; ++s) {
        long i = base + (long)s * BO;
        float fv = (float)f_h[i];
        float xv = (float)xp_h[i];
        float rv = (float)r_h[i];
        float cxv = (float)cx_h[i];
        c = fv * c + (1.f - fv) * xv;
        float e = __expf(2.f * c);                       // tanh = (e-1)/(e+1)
        float th = (e - 1.f) * __builtin_amdgcn_rcpf(e + 1.f);
        ht[i] = rv * th + (1.f - rv) * cxv;
    }
}

// ---------------- launcher ----------------
extern "C" void kernel_launch(void* const* d_in, const int* in_sizes, int n_in,
                              void* d_out, int out_size, void* d_ws, size_t ws_size,
                              hipStream_t stream) {
    const float* xt  = (const float*)d_in[0];
    const float* ct0 = (const float*)d_in[1];
    const float* Wx  = (const float*)d_in[2];
    const float* Wf  = (const float*)d_in[3];
    const float* bf_ = (const float*)d_in[4];
    const float* Wr  = (const float*)d_in[5];
    const float* br_ = (const float*)d_in[6];
    const float* Wc  = (const float*)d_in[7];
    const float* bc_ = (const float*)d_in[8];

    float* ht      = (float*)d_out;
    float* c_final = ht + (size_t)MROWS * NOUT;

    char* ws = (char*)d_ws;
    _Float16* Wcat = (_Float16*)ws;                          // 1 MiB
    _Float16* xh   = (_Float16*)(ws + (1 << 20));            // 64 MiB
    _Float16* xp_h = xh + (size_t)MROWS * NIN;               // 32 MiB each
    _Float16* f_h  = xp_h + (size_t)MROWS * NOUT;
    _Float16* r_h  = f_h  + (size_t)MROWS * NOUT;
    _Float16* cx_h = r_h  + (size_t)MROWS * NOUT;
    float* chunkA  = (float*)(cx_h + (size_t)MROWS * NOUT);  // 1 MiB
    float* chunkB  = chunkA + NCHUNK * BO;
    float* cin     = chunkB + NCHUNK * BO;

    convert_w<<<512, 256, 0, stream>>>(Wx, Wf, Wr, Wc, Wcat);
    convert_x<<<(MROWS * NIN / 8) / 256, 256, 0, stream>>>(xt, xh);
    gemm_proj<<<256, 512, 0, stream>>>(
        xh, Wcat, bf_, br_, bc_, xp_h, f_h, r_h, cx_h);
    chunk_scan_a<<<(NCHUNK * BO) / 256, 256, 0, stream>>>(f_h, xp_h, chunkA, chunkB);
    chunk_prop<<<BO / 256, 256, 0, stream>>>(ct0, chunkA, chunkB, cin, c_final);
    chunk_scan_h<<<(NCHUNK * BO) / 256, 256, 0, stream>>>(xp_h, f_h, r_h, cx_h, cin, ht);
}